// Round 3
// baseline (184.444 us; speedup 1.0000x reference)
//
#include <hip/hip_runtime.h>

// SWD18: per-feature cyclic window-of-5 sort (verified reduction, absmax=0 in R1/R2):
// for column i, sort rows {5m + (i%5) + j mod L, j=0..4} in place. q,k are dead inputs.
//
// R3: barrier-free register-streaming kernel. R2's LDS 3-phase version was
// latency-bound (block lifetime ~21us vs ~1us of issued work; 2.4 TB/s HBM,
// VALUBusy 12%): short-lived blocks convoyed on vmcnt(0)+s_barrier. Here each
// thread streams a 50-row strip of 4 consecutive columns (one float4 slot):
// rolling 5-row groups, per-column window assembly / 9-comparator sort /
// output scatter done with residue muxes (v_cndmask chains) in registers.
// All global traffic is contiguous 1KB-per-wave float4 streams; zero LDS,
// zero barriers; 1280 long-lived waves = 5/CU with next-group loads
// prefetched at the top of each iteration.

constexpr int L = 4000;
constexpr int D = 512;
constexpr int S = 50;                 // output rows per thread (10 windows)
constexpr int NSTRIPS = L / S;        // 80
constexpr int NCG = D / 4;            // 128 float4 column-groups

// 9-comparator optimal sorting network for 5, ascending
#define CE(a, b) { float lo_ = fminf(a, b); float hi_ = fmaxf(a, b); (a) = lo_; (b) = hi_; }

// Process one column (component C of the float4 rows) with residue RC.
// pg[] = previous group raw rows, cg_[] = current group raw rows,
// ogb[] = output staging carried from previous iteration (rows of group k),
// fa[]  = finalized rows of group k-1 (flush after this), nb[] = new carry.
// Window m=k-1 = [prev[RC..4], cur[0..RC-1]]; sorted s_i -> row 5(k-1)+RC+i.
#define PROC_COL(C, RC)                                                          \
  {                                                                              \
    const bool e0 = (RC) == 0, e1 = (RC) == 1, e2 = (RC) == 2, e3 = (RC) == 3;   \
    float W0 = e0 ? pg[0].C : e1 ? pg[1].C : e2 ? pg[2].C : e3 ? pg[3].C : pg[4].C;  \
    float W1 = e0 ? pg[1].C : e1 ? pg[2].C : e2 ? pg[3].C : e3 ? pg[4].C : cg_[0].C; \
    float W2 = e0 ? pg[2].C : e1 ? pg[3].C : e2 ? pg[4].C : e3 ? cg_[0].C : cg_[1].C;\
    float W3 = e0 ? pg[3].C : e1 ? pg[4].C : e2 ? cg_[0].C : e3 ? cg_[1].C : cg_[2].C;\
    float W4 = e0 ? pg[4].C : e1 ? cg_[0].C : e2 ? cg_[1].C : e3 ? cg_[2].C : cg_[3].C;\
    CE(W0, W1) CE(W3, W4) CE(W2, W4) CE(W2, W3) CE(W1, W4)                       \
    CE(W0, W3) CE(W0, W2) CE(W1, W3) CE(W1, W2)                                  \
    fa[0].C = e0 ? W0 : ogb[0].C;                                                \
    fa[1].C = e0 ? W1 : e1 ? W0 : ogb[1].C;                                      \
    fa[2].C = e0 ? W2 : e1 ? W1 : e2 ? W0 : ogb[2].C;                            \
    fa[3].C = e0 ? W3 : e1 ? W2 : e2 ? W1 : e3 ? W0 : ogb[3].C;                  \
    fa[4].C = e0 ? W4 : e1 ? W3 : e2 ? W2 : e3 ? W1 : W0;                        \
    nb[0].C = e1 ? W4 : e2 ? W3 : e3 ? W2 : W1;  /* valid iff RC>0 */            \
    nb[1].C = e2 ? W4 : e3 ? W3 : W2;            /* valid iff RC>1 */            \
    nb[2].C = e3 ? W4 : W3;                      /* valid iff RC>2 */            \
    nb[3].C = W4;                                /* valid iff RC>3 */            \
    nb[4].C = W4;                                /* never used     */            \
  }

__global__ __launch_bounds__(64)
void swd18_stream(const float* __restrict__ v, float* __restrict__ out) {
    const int tid   = blockIdx.x * 64 + threadIdx.x;
    const int cgidx = tid & (NCG - 1);          // float4 column-group 0..127
    const int rem   = tid >> 7;
    const int strip = rem % NSTRIPS;            // 0..79
    const int b     = rem / NSTRIPS;            // batch

    const int R0 = strip * S;                   // multiple of 5
    const float* __restrict__ vb = v   + (size_t)b * (L * D) + cgidx * 4;
    float*       __restrict__ ob = out + (size_t)b * (L * D) + cgidx * 4;

    const int rc0 = (4 * cgidx) % 5;
    const int rc1 = (rc0 + 1) % 5;
    const int rc2 = (rc0 + 2) % 5;
    const int rc3 = (rc0 + 3) % 5;

    float4 pg[5], cg_[5], ogb[5];

    // preload group k0-1 (rows R0-5..R0-1, cyclic) and group k0 (rows R0..R0+4)
    int prow = R0 - 5; if (prow < 0) prow += L;
#pragma unroll
    for (int j = 0; j < 5; ++j) pg[j]  = *(const float4*)(vb + (size_t)(prow + j) * D);
#pragma unroll
    for (int j = 0; j < 5; ++j) cg_[j] = *(const float4*)(vb + (size_t)(R0 + j) * D);
#pragma unroll
    for (int j = 0; j < 5; ++j) ogb[j] = make_float4(0.f, 0.f, 0.f, 0.f);

#pragma unroll
    for (int k = 0; k <= S / 5; ++k) {          // groups k0 .. k0+10
        // prefetch next group (rows R0+5(k+1)..+4, cyclic; contiguous, 5-aligned)
        float4 ng[5];
        if (k < S / 5) {
            int nbase = R0 + 5 * (k + 1);
            if (nbase >= L) nbase -= L;
#pragma unroll
            for (int j = 0; j < 5; ++j) ng[j] = *(const float4*)(vb + (size_t)(nbase + j) * D);
        }

        float4 fa[5], nb[5];
        PROC_COL(x, rc0)
        PROC_COL(y, rc1)
        PROC_COL(z, rc2)
        PROC_COL(w, rc3)

        // flush finalized rows of group k-1 (skip k==0: those belong to prev strip)
        if (k > 0) {
            const int obase = R0 + 5 * k - 5;   // in [R0, R0+45], never wraps
#pragma unroll
            for (int j = 0; j < 5; ++j)
                *(float4*)(ob + (size_t)(obase + j) * D) = fa[j];
        }

        // rotate
#pragma unroll
        for (int j = 0; j < 5; ++j) {
            pg[j]  = cg_[j];
            if (k < S / 5) cg_[j] = ng[j];
            ogb[j] = nb[j];
        }
    }
}

#undef PROC_COL
#undef CE

extern "C" void kernel_launch(void* const* d_in, const int* in_sizes, int n_in,
                              void* d_out, int out_size, void* d_ws, size_t ws_size,
                              hipStream_t stream) {
    // setup_inputs order: q, k, v — only v is used by the reference forward.
    const float* v = (const float*)d_in[2];
    float* out = (float*)d_out;

    const int B = in_sizes[2] / (L * D);        // 8 for the bench shape
    const int nthreads = NCG * NSTRIPS * B;     // 81920 for B=8
    swd18_stream<<<dim3(nthreads / 64), dim3(64), 0, stream>>>(v, out);
}

// Round 5
// 178.938 us; speedup vs baseline: 1.0308x; 1.0308x over previous
//
#include <hip/hip_runtime.h>

// SWD18: per-feature cyclic window-of-5 sort (reduction verified absmax=0 in R1-R3):
// for column i, sort rows {5m + (i%5) + j mod L, j=0..4} ascending, in place.
// q, k are dead inputs.
//
// R5 = R4 with compile fix: __builtin_nontemporal_store needs a NATIVE vector
// type, not HIP's float4 class -> use ext_vector_type(4) float alias.
//
// R4 design: one-shot threads — fixes all three prior flaws simultaneously:
//   R1 flaw: partial-line writes (1.76x WRITE amp)  -> full float4 lines here
//   R2 flaw: barrier convoys                        -> zero barriers/LDS here
//   R3 flaw: 3.8 waves/CU, 10% load duty cycle      -> 12800 one-shot waves,
//            15 float4 loads issued back-to-back per thread, then die.
// Thread (b, g, cg): loads row-groups g-1, g, g+1 (15 rows) at its float4
// column slot, computes windows g-1 and g per column (window g-1 recomputed
// redundantly by neighbor threads -> no cross-thread carry), writes output
// rows 5g..5g+4 as full-line nontemporal float4 stores. Each output element
// written exactly once device-wide; reads 3x logical, L2/L3-absorbed.

constexpr int L = 4000;
constexpr int D = 512;
constexpr int NCG = D / 4;            // 128 float4 column-groups
constexpr int NG  = L / 5;            // 800 row-groups

typedef float vf4 __attribute__((ext_vector_type(4)));   // native vec for builtins

// optimal 9-comparator sorting network for 5, ascending
#define CE(a, b) { float lo_ = fminf(a, b); float hi_ = fmaxf(a, b); (a) = lo_; (b) = hi_; }

// One column (component C = 0..3 of the vf4 rows), runtime residue RC.
// Window A = g-1: pg[RC..4], cg_[0..RC-1]; window B = g: cg_[RC..4], ng[0..RC-1].
// Output row 5g+t = (t < RC) ? A[t+5-RC] : B[t-RC].
#define PROC_COL(C, RC)                                                            \
  {                                                                                \
    const bool e0 = (RC) == 0, e1 = (RC) == 1, e2 = (RC) == 2, e3 = (RC) == 3;     \
    float A0 = e0 ? pg[0][C] : e1 ? pg[1][C] : e2 ? pg[2][C] : e3 ? pg[3][C] : pg[4][C];  \
    float A1 = e0 ? pg[1][C] : e1 ? pg[2][C] : e2 ? pg[3][C] : e3 ? pg[4][C] : cg_[0][C]; \
    float A2 = e0 ? pg[2][C] : e1 ? pg[3][C] : e2 ? pg[4][C] : e3 ? cg_[0][C] : cg_[1][C];\
    float A3 = e0 ? pg[3][C] : e1 ? pg[4][C] : e2 ? cg_[0][C] : e3 ? cg_[1][C] : cg_[2][C];\
    float A4 = e0 ? pg[4][C] : e1 ? cg_[0][C] : e2 ? cg_[1][C] : e3 ? cg_[2][C] : cg_[3][C];\
    float B0 = e0 ? cg_[0][C] : e1 ? cg_[1][C] : e2 ? cg_[2][C] : e3 ? cg_[3][C] : cg_[4][C];\
    float B1 = e0 ? cg_[1][C] : e1 ? cg_[2][C] : e2 ? cg_[3][C] : e3 ? cg_[4][C] : ng[0][C]; \
    float B2 = e0 ? cg_[2][C] : e1 ? cg_[3][C] : e2 ? cg_[4][C] : e3 ? ng[0][C] : ng[1][C];  \
    float B3 = e0 ? cg_[3][C] : e1 ? cg_[4][C] : e2 ? ng[0][C] : e3 ? ng[1][C] : ng[2][C];   \
    float B4 = e0 ? cg_[4][C] : e1 ? ng[0][C] : e2 ? ng[1][C] : e3 ? ng[2][C] : ng[3][C];    \
    CE(A0, A1) CE(A3, A4) CE(A2, A4) CE(A2, A3) CE(A1, A4)                         \
    CE(A0, A3) CE(A0, A2) CE(A1, A3) CE(A1, A2)                                    \
    CE(B0, B1) CE(B3, B4) CE(B2, B4) CE(B2, B3) CE(B1, B4)                         \
    CE(B0, B3) CE(B0, B2) CE(B1, B3) CE(B1, B2)                                    \
    fa[0][C] = e0 ? B0 : e1 ? A4 : e2 ? A3 : e3 ? A2 : A1;                         \
    fa[1][C] = e0 ? B1 : e1 ? B0 : e2 ? A4 : e3 ? A3 : A2;                         \
    fa[2][C] = e0 ? B2 : e1 ? B1 : e2 ? B0 : e3 ? A4 : A3;                         \
    fa[3][C] = e0 ? B3 : e1 ? B2 : e2 ? B1 : e3 ? B0 : A4;                         \
    fa[4][C] = e0 ? B4 : e1 ? B3 : e2 ? B2 : e3 ? B1 : B0;                         \
  }

__global__ __launch_bounds__(256)
void swd18_oneshot(const float* __restrict__ v, float* __restrict__ out) {
    const int tid = blockIdx.x * 256 + threadIdx.x;
    const int cg  = tid & (NCG - 1);            // float4 column-group 0..127
    const int rem = tid >> 7;
    const int g   = rem % NG;                   // row-group 0..799
    const int b   = rem / NG;                   // batch

    const float* __restrict__ vb = v   + (size_t)b * (L * D) + cg * 4;
    float*       __restrict__ ob = out + (size_t)b * (L * D) + cg * 4;

    const int r0 = 5 * g;                       // this thread's output rows
    int rp = r0 - 5; if (rp < 0)  rp += L;      // group g-1 base (wraps at g=0)
    int rn = r0 + 5; if (rn >= L) rn -= L;      // group g+1 base (wraps at g=799)

    vf4 pg[5], cg_[5], ng[5];
#pragma unroll
    for (int j = 0; j < 5; ++j) pg[j]  = *(const vf4*)(vb + (size_t)(rp + j) * D);
#pragma unroll
    for (int j = 0; j < 5; ++j) cg_[j] = *(const vf4*)(vb + (size_t)(r0 + j) * D);
#pragma unroll
    for (int j = 0; j < 5; ++j) ng[j]  = *(const vf4*)(vb + (size_t)(rn + j) * D);

    const int rc0 = (4 * cg) % 5;
    const int rc1 = (rc0 + 1) % 5;
    const int rc2 = (rc0 + 2) % 5;
    const int rc3 = (rc0 + 3) % 5;

    vf4 fa[5];
    PROC_COL(0, rc0)
    PROC_COL(1, rc1)
    PROC_COL(2, rc2)
    PROC_COL(3, rc3)

#pragma unroll
    for (int j = 0; j < 5; ++j)
        __builtin_nontemporal_store(fa[j], (vf4*)(ob + (size_t)(r0 + j) * D));
}

#undef PROC_COL
#undef CE

extern "C" void kernel_launch(void* const* d_in, const int* in_sizes, int n_in,
                              void* d_out, int out_size, void* d_ws, size_t ws_size,
                              hipStream_t stream) {
    // setup_inputs order: q, k, v — only v is used by the reference forward.
    const float* v = (const float*)d_in[2];
    float* out = (float*)d_out;

    const int B = in_sizes[2] / (L * D);        // 8 for the bench shape
    const int nthreads = NCG * NG * B;          // 819200 for B=8
    swd18_oneshot<<<dim3(nthreads / 256), dim3(256), 0, stream>>>(v, out);
}